// Round 8
// baseline (329.367 us; speedup 1.0000x reference)
//
#include <hip/hip_runtime.h>
#include <math.h>
#include <stdint.h>

constexpr int N   = 50000;
constexpr int E   = 800000;
constexpr int IN  = 128;
constexpr int H   = 256;
constexpr int OUT = 10;
constexpr int G   = 512;
constexpr int BSTR = 64;    // per-node bucket stride
constexpr int P    = (N + 31) / 32;   // 1563 partitions of 32 nodes
constexpr int CAP  = 256;   // per-(xcd,partition) capacity; mean 64, ~24 sigma

typedef __bf16 bf16x8 __attribute__((ext_vector_type(8)));
typedef float  f32x4  __attribute__((ext_vector_type(4)));
typedef float  f32x2  __attribute__((ext_vector_type(2)));

__device__ __forceinline__ float blo(unsigned v) { return __uint_as_float(v << 16); }
__device__ __forceinline__ float bhi(unsigned v) { return __uint_as_float(v & 0xffff0000u); }
__device__ __forceinline__ unsigned short f2b(float f) {
  unsigned u = __float_as_uint(f);
  u += 0x7fffu + ((u >> 16) & 1u);   // RNE (no NaNs in this net)
  return (unsigned short)(u >> 16);
}
__device__ __forceinline__ unsigned packb(float lo, float hi) {
  return (unsigned)f2b(lo) | ((unsigned)f2b(hi) << 16);
}
__device__ __forceinline__ unsigned pk_fp8x4(float a, float b, float c, float d) {
  int r = 0;
  r = __builtin_amdgcn_cvt_pk_fp8_f32(a, b, r, false);
  r = __builtin_amdgcn_cvt_pk_fp8_f32(c, d, r, true);
  return (unsigned)r;
}
__device__ __forceinline__ unsigned char fp8_1(float v) {
  return (unsigned char)(__builtin_amdgcn_cvt_pk_fp8_f32(v, v, 0, false) & 0xff);
}

// ---------------- prep: edge binning (phase A) + x->fp8 + 4 weight transposes ----------------
// section layout: [0,EA) phaseA ; [EA, EA+XQ) x->fp8 ; then W1a ; then 3x WH

constexpr int EA_BLOCKS  = E / 256;                 // 3125 (exact)
constexpr int XQ_BLOCKS  = (N * IN / 4) / 256;      // 6250 (exact)
constexpr int W1A_BLOCKS = (256 * IN) / 256;        // 128
constexpr int WH_BLOCKS  = (256 * H) / 256;         // 256

__global__ void prep_kernel(const int* __restrict__ srcp, const int* __restrict__ dstp,
                            int* __restrict__ pcount, unsigned* __restrict__ pbuf,
                            const float* __restrict__ x, unsigned* __restrict__ xq,
                            const float* __restrict__ W1a, unsigned short* __restrict__ Wt1a,
                            const float* __restrict__ W1b, unsigned short* __restrict__ Wt1b,
                            const float* __restrict__ W2a, unsigned short* __restrict__ Wt2a,
                            const float* __restrict__ W2b, unsigned short* __restrict__ Wt2b) {
  int b = blockIdx.x;
  int t = threadIdx.x;
  if (b < EA_BLOCKS) {
    // phase A: bin edges into per-XCD per-partition buffers (no cross-XCD line sharing)
    int e = b * 256 + t;
    int d = dstp[e], s = srcp[e];
    int part = d >> 5;
    int slot = ((b & 7) * P) + part;        // blockIdx%8 ~ XCD (locality heuristic only)
    int pos = atomicAdd(&pcount[slot], 1);
    if (pos < CAP) pbuf[(size_t)slot * CAP + pos] = ((unsigned)(d & 31) << 16) | (unsigned)s;
    return;
  }
  b -= EA_BLOCKS;
  if (b < XQ_BLOCKS) {
    int id = b * 256 + t;
    float4 v = ((const float4*)x)[id];
    xq[id] = pk_fp8x4(v.x, v.y, v.z, v.w);
    return;
  }
  b -= XQ_BLOCKS;
  if (b < W1A_BLOCKS) {
    int id = b * 256 + t;               // id = n*128 + k
    int n = id >> 7, k = id & 127;
    Wt1a[id] = f2b(W1a[k * 256 + n]);
    return;
  }
  b -= W1A_BLOCKS;
  const float* Ws;
  unsigned short* Wd;
  if (b < WH_BLOCKS)            { Ws = W1b; Wd = Wt1b; }
  else if (b < 2 * WH_BLOCKS)   { Ws = W2a; Wd = Wt2a; b -= WH_BLOCKS; }
  else                          { Ws = W2b; Wd = Wt2b; b -= 2 * WH_BLOCKS; }
  int id = b * 256 + t;                 // id = n*256 + k
  int n = id >> 8, k = id & 255;
  Wd[id] = f2b(Ws[k * 256 + n]);
}

// ---------------- phase B: drain partition buffers -> bucket CSR + deg ----------------

__global__ __launch_bounds__(256) void csr_kernel(const unsigned* __restrict__ pbuf,
                                                  const int* __restrict__ pcount,
                                                  int* __restrict__ deg, int* __restrict__ csre) {
  __shared__ int ldeg[32];
  int p = blockIdx.x;
  int t = threadIdx.x;
  if (t < 32) ldeg[t] = 0;
  __syncthreads();
  for (int x = 0; x < 8; ++x) {
    int slot = x * P + p;
    int cnt = pcount[slot]; if (cnt > CAP) cnt = CAP;
    const unsigned* seg = pbuf + (size_t)slot * CAP;
    for (int k = t; k < cnt; k += 256) {
      unsigned v = seg[k];
      int dl = v >> 16, s = (int)(v & 0xFFFFu);
      int pos = atomicAdd(&ldeg[dl], 1);
      if (pos < BSTR) csre[((size_t)p * 32 + dl) * BSTR + pos] = s;
    }
  }
  __syncthreads();
  if (t < 32) {
    int node = p * 32 + t;
    if (node < N) deg[node] = min(ldeg[t], BSTR);
  }
}

// ---------------- chunked fp8 gather aggregation ----------------
// out_bf16[i] = (1+eps)*in[i] + sum_nbr in[j]; row = RS fp8 bytes, processed in 64-byte
// column chunks (3.2 MB table slice < 4 MB per-XCD L2; 1D x-major grid gives temporal order).
// Block = 256 thr = 4 waves; wave = 4 nodes x 16 lanes x dword.

template <int RS>   // 128 (agg1) or 256 (agg2)
__global__ __launch_bounds__(256) void agg_fp8_kernel(
    const unsigned char* __restrict__ inq,
    const int* __restrict__ deg, const int* __restrict__ csre,
    const float* __restrict__ epsp, unsigned short* __restrict__ out) {
  constexpr int NB = N / 16;          // 3125 blocks per chunk-pass (exact)
  int bx = blockIdx.x;
  int q  = bx / NB;                   // chunk id (temporally ordered)
  int pb = bx - q * NB;
  int tid = threadIdx.x;
  int wave = tid >> 6, lane = tid & 63;
  int g = lane >> 4, l = lane & 15;
  int i = pb * 16 + wave * 4 + g;     // node (always < N: 3125*16 == N)
  int dg = deg[i]; if (dg > BSTR) dg = BSTR;
  const int* bkt = csre + (size_t)i * BSTR;
  int dgmax = max(dg, __shfl_xor(dg, 16));
  dgmax = max(dgmax, __shfl_xor(dgmax, 32));
  const unsigned char* cb = inq + q * 64 + l * 4;   // + idx*RS
  float a0 = 0.f, a1 = 0.f, a2 = 0.f, a3 = 0.f;
  int j = 0;
  for (; j + 8 <= dgmax; j += 8) {
    unsigned idx[8], v[8];
#pragma unroll
    for (int u = 0; u < 8; ++u) {
      int jc = j + u; if (jc > dg - 1) jc = dg - 1; if (jc < 0) jc = 0;
      unsigned raw = (unsigned)bkt[jc];
      idx[u] = raw < (unsigned)N ? raw : (unsigned)(N - 1);   // poison-safe
    }
#pragma unroll
    for (int u = 0; u < 8; ++u) v[u] = *(const unsigned*)(cb + (size_t)idx[u] * RS);
#pragma unroll
    for (int u = 0; u < 8; ++u) {
      float s = (j + u < dg) ? 1.f : 0.f;
      f32x2 lo = __builtin_amdgcn_cvt_pk_f32_fp8((int)v[u], false);
      f32x2 hi = __builtin_amdgcn_cvt_pk_f32_fp8((int)v[u], true);
      a0 += s * lo.x; a1 += s * lo.y; a2 += s * hi.x; a3 += s * hi.y;
    }
  }
  for (; j < dgmax; ++j) {
    int jc = j; if (jc > dg - 1) jc = dg - 1; if (jc < 0) jc = 0;
    unsigned raw = (unsigned)bkt[jc];
    unsigned idx = raw < (unsigned)N ? raw : (unsigned)(N - 1);
    unsigned v = *(const unsigned*)(cb + (size_t)idx * RS);
    float s = (j < dg) ? 1.f : 0.f;
    f32x2 lo = __builtin_amdgcn_cvt_pk_f32_fp8((int)v, false);
    f32x2 hi = __builtin_amdgcn_cvt_pk_f32_fp8((int)v, true);
    a0 += s * lo.x; a1 += s * lo.y; a2 += s * hi.x; a3 += s * hi.y;
  }
  float sc = 1.0f + epsp[0];
  unsigned sv = *(const unsigned*)(cb + (size_t)i * RS);
  f32x2 slo = __builtin_amdgcn_cvt_pk_f32_fp8((int)sv, false);
  f32x2 shi = __builtin_amdgcn_cvt_pk_f32_fp8((int)sv, true);
  a0 += sc * slo.x; a1 += sc * slo.y; a2 += sc * shi.x; a3 += sc * shi.y;
  unsigned short* orow = out + (size_t)i * RS + q * 64 + l * 4;
  *(uint2*)orow = make_uint2(packb(a0, a1), packb(a2, a3));
}

// ---------------- bf16 MFMA GEMM: out[N][256] = act(A[N][K] @ W + b) ----------------
// proven structure: 128x128 tile, BK=32, 4 waves, LDK=40 (0 conflicts). OUT8 -> fp8 output.

template <int K, bool RELU, bool OUT8>
__global__ __launch_bounds__(256, 2) void gemm_bf16_kernel(const unsigned short* __restrict__ A,
                                                           const unsigned short* __restrict__ Bt,
                                                           const float* __restrict__ bias,
                                                           void* __restrict__ outv,
                                                           int Nrows) {
  constexpr int M = 256, LDK = 40;
  __shared__ __align__(16) unsigned short As[128 * LDK];
  __shared__ __align__(16) unsigned short Bs[128 * LDK];
  const int tid  = threadIdx.x;
  const int r0   = blockIdx.x * 128;
  const int c0   = blockIdx.y * 128;
  const int wave = tid >> 6, lane = tid & 63;
  const int quad = lane >> 4, l15 = lane & 15;
  const int wrow = (wave >> 1) * 64, wcol = (wave & 1) * 64;
  const int srow = tid >> 2;
  const int sk8  = (tid & 3) * 8;

  f32x4 acc[4][4];
#pragma unroll
  for (int i = 0; i < 4; ++i)
#pragma unroll
    for (int j = 0; j < 4; ++j) acc[i][j] = (f32x4){0.f, 0.f, 0.f, 0.f};

  for (int k0 = 0; k0 < K; k0 += 32) {
    {
      int row = srow, grow = r0 + row;
      uint4 v = make_uint4(0u, 0u, 0u, 0u);
      if (grow < Nrows) v = *(const uint4*)(A + (size_t)grow * K + k0 + sk8);
      *(uint4*)(As + row * LDK + sk8) = v;
      row += 64; grow = r0 + row;
      uint4 w = make_uint4(0u, 0u, 0u, 0u);
      if (grow < Nrows) w = *(const uint4*)(A + (size_t)grow * K + k0 + sk8);
      *(uint4*)(As + row * LDK + sk8) = w;
      *(uint4*)(Bs + srow * LDK + sk8) =
          *(const uint4*)(Bt + (size_t)(c0 + srow) * K + k0 + sk8);
      *(uint4*)(Bs + (srow + 64) * LDK + sk8) =
          *(const uint4*)(Bt + (size_t)(c0 + srow + 64) * K + k0 + sk8);
    }
    __syncthreads();
    bf16x8 af[4], bfr[4];
#pragma unroll
    for (int mt = 0; mt < 4; ++mt)
      af[mt] = *(const bf16x8*)(As + (wrow + mt * 16 + l15) * LDK + quad * 8);
#pragma unroll
    for (int nt = 0; nt < 4; ++nt)
      bfr[nt] = *(const bf16x8*)(Bs + (wcol + nt * 16 + l15) * LDK + quad * 8);
#pragma unroll
    for (int mt = 0; mt < 4; ++mt)
#pragma unroll
      for (int nt = 0; nt < 4; ++nt)
        acc[mt][nt] = __builtin_amdgcn_mfma_f32_16x16x32_bf16(af[mt], bfr[nt], acc[mt][nt], 0, 0, 0);
    __syncthreads();
  }

  float bv[4];
#pragma unroll
  for (int nt = 0; nt < 4; ++nt) bv[nt] = bias[c0 + wcol + nt * 16 + l15];
#pragma unroll
  for (int mt = 0; mt < 4; ++mt) {
    int gr0 = r0 + wrow + mt * 16 + quad * 4;
#pragma unroll
    for (int i = 0; i < 4; ++i) {
      int grow = gr0 + i;
      if (grow >= Nrows) continue;
#pragma unroll
      for (int nt = 0; nt < 4; ++nt) {
        float v = acc[mt][nt][i] + bv[nt];
        if (RELU) v = fmaxf(v, 0.f);
        int col = c0 + wcol + nt * 16 + l15;
        if (OUT8) ((unsigned char*)outv)[(size_t)grow * M + col] = fp8_1(v);
        else      ((unsigned short*)outv)[(size_t)grow * M + col] = f2b(v);
      }
    }
  }
}

// ---------------- fused mean-pool + classifier + log_softmax ----------------

__global__ __launch_bounds__(128) void pool_final_kernel(const unsigned short* __restrict__ h2,
                                                         const int* __restrict__ batch,
                                                         const float* __restrict__ Wlin,
                                                         const float* __restrict__ blin,
                                                         float* __restrict__ out) {
  __shared__ float sp[H];
  __shared__ float logits[OUT];
  int g = blockIdx.x;
  int t = threadIdx.x;  // 128, 2 cols each
  int lo = 0, hi = N;
  while (lo < hi) { int m = (lo + hi) >> 1; if (batch[m] < g) lo = m + 1; else hi = m; }
  int s = lo;
  lo = 0; hi = N;
  while (lo < hi) { int m = (lo + hi) >> 1; if (batch[m] < g + 1) lo = m + 1; else hi = m; }
  int e = lo;
  float a0 = 0.f, a1 = 0.f;
  const unsigned* base = (const unsigned*)h2;
  int n = s;
  for (; n + 4 <= e; n += 4) {
    unsigned v0 = base[(size_t)(n + 0) * (H / 2) + t];
    unsigned v1 = base[(size_t)(n + 1) * (H / 2) + t];
    unsigned v2 = base[(size_t)(n + 2) * (H / 2) + t];
    unsigned v3 = base[(size_t)(n + 3) * (H / 2) + t];
    a0 += blo(v0) + blo(v1) + blo(v2) + blo(v3);
    a1 += bhi(v0) + bhi(v1) + bhi(v2) + bhi(v3);
  }
  for (; n < e; ++n) {
    unsigned v = base[(size_t)n * (H / 2) + t];
    a0 += blo(v); a1 += bhi(v);
  }
  float inv = 1.0f / fmaxf((float)(e - s), 1.0f);
  sp[2 * t]     = a0 * inv;
  sp[2 * t + 1] = a1 * inv;
  __syncthreads();
  if (t < OUT) {
    float acc = blin[t];
    for (int k = 0; k < H; ++k) acc = fmaf(sp[k], Wlin[k * OUT + t], acc);
    logits[t] = acc;
  }
  __syncthreads();
  if (t == 0) {
    float m = -INFINITY;
    for (int j = 0; j < OUT; ++j) m = fmaxf(m, logits[j]);
    float ssum = 0.f;
    for (int j = 0; j < OUT; ++j) ssum += expf(logits[j] - m);
    float ls = logf(ssum);
    for (int j = 0; j < OUT; ++j) out[(size_t)g * OUT + j] = logits[j] - m - ls;
  }
}

// ---------------- launch ----------------

static inline char* align_up(char* p, size_t a) {
  return (char*)(((uintptr_t)p + a - 1) & ~(a - 1));
}

extern "C" void kernel_launch(void* const* d_in, const int* in_sizes, int n_in,
                              void* d_out, int out_size, void* d_ws, size_t ws_size,
                              hipStream_t stream) {
  const float* x    = (const float*)d_in[0];
  const int*   ei   = (const int*)d_in[1];
  const int*   srcp = ei;
  const int*   dstp = ei + E;
  const int*   batch = (const int*)d_in[2];
  const float* eps1 = (const float*)d_in[3];
  const float* W1a  = (const float*)d_in[4];
  const float* b1a  = (const float*)d_in[5];
  const float* W1b  = (const float*)d_in[6];
  const float* b1b  = (const float*)d_in[7];
  const float* eps2 = (const float*)d_in[8];
  const float* W2a  = (const float*)d_in[9];
  const float* b2a  = (const float*)d_in[10];
  const float* W2b  = (const float*)d_in[11];
  const float* b2b  = (const float*)d_in[12];
  const float* Wlin = (const float*)d_in[13];
  const float* blin = (const float*)d_in[14];
  float* outp = (float*)d_out;

  char* p = (char*)d_ws;
  int* pcount = (int*)p;             p = align_up(p + (size_t)8 * P * 4, 256);
  unsigned* pbuf = (unsigned*)p;     p = align_up(p + (size_t)8 * P * CAP * 4, 256);
  int* deg  = (int*)p;               p = align_up(p + (size_t)N * 4, 256);
  int* csre = (int*)p;               p = align_up(p + (size_t)N * BSTR * 4, 256);
  unsigned* xq = (unsigned*)p;       p = align_up(p + (size_t)N * IN, 256);          // fp8 x
  unsigned char* h1q = (unsigned char*)p;  p = align_up(p + (size_t)N * H, 256);     // fp8 h1
  unsigned short* B1 = (unsigned short*)p; p = align_up(p + (size_t)N * IN * 2, 256);
  unsigned short* B2 = (unsigned short*)p; p = align_up(p + (size_t)N * H * 2, 256);
  unsigned short* B3 = (unsigned short*)p; p = align_up(p + (size_t)N * H * 2, 256);
  unsigned short* Wt1a = (unsigned short*)p;  p = align_up(p + (size_t)H * IN * 2, 256);
  unsigned short* Wt1b = (unsigned short*)p;  p = align_up(p + (size_t)H * H * 2, 256);
  unsigned short* Wt2a = (unsigned short*)p;  p = align_up(p + (size_t)H * H * 2, 256);
  unsigned short* Wt2b = (unsigned short*)p;  p = align_up(p + (size_t)H * H * 2, 256);

  // 0: zero partition counters (tiny)
  hipMemsetAsync(pcount, 0, (size_t)8 * P * 4, stream);

  // 1: prep (edge binning + x->fp8 + weight transposes)
  prep_kernel<<<EA_BLOCKS + XQ_BLOCKS + W1A_BLOCKS + 3 * WH_BLOCKS, 256, 0, stream>>>(
      srcp, dstp, pcount, pbuf, x, xq, W1a, Wt1a, W1b, Wt1b, W2a, Wt2a, W2b, Wt2b);

  // 2: drain bins -> bucket CSR + deg
  csr_kernel<<<P, 256, 0, stream>>>(pbuf, pcount, deg, csre);

  const dim3 ggrid((N + 127) / 128, 2);

  // layer 1
  agg_fp8_kernel<IN><<<2 * (N / 16), 256, 0, stream>>>((const unsigned char*)xq, deg, csre, eps1, B1);
  gemm_bf16_kernel<IN, true, false><<<ggrid, 256, 0, stream>>>(B1, Wt1a, b1a, B2, N);
  gemm_bf16_kernel<H, true, true><<<ggrid, 256, 0, stream>>>(B2, Wt1b, b1b, h1q, N);  // h1 -> fp8

  // layer 2
  agg_fp8_kernel<H><<<4 * (N / 16), 256, 0, stream>>>(h1q, deg, csre, eps2, B3);
  gemm_bf16_kernel<H, true, false><<<ggrid, 256, 0, stream>>>(B3, Wt2a, b2a, B2, N);
  gemm_bf16_kernel<H, false, false><<<ggrid, 256, 0, stream>>>(B2, Wt2b, b2b, B3, N); // B3 = h2

  // pool + classify
  pool_final_kernel<<<G, 128, 0, stream>>>(B3, batch, Wlin, blin, outp);
}

// Round 9
// 319.640 us; speedup vs baseline: 1.0304x; 1.0304x over previous
//
#include <hip/hip_runtime.h>
#include <math.h>
#include <stdint.h>

constexpr int N   = 50000;
constexpr int E   = 800000;
constexpr int IN  = 128;
constexpr int H   = 256;
constexpr int OUT = 10;
constexpr int G   = 512;
constexpr int BSTR = 64;    // per-node bucket stride
constexpr int P    = (N + 31) / 32;   // 1563 partitions of 32 nodes
constexpr int CAP  = 256;   // per-(xcd,partition) capacity; mean 64, ~24 sigma

typedef __bf16 bf16x8 __attribute__((ext_vector_type(8)));
typedef float  f32x4  __attribute__((ext_vector_type(4)));
typedef float  f32x2  __attribute__((ext_vector_type(2)));

__device__ __forceinline__ float blo(unsigned v) { return __uint_as_float(v << 16); }
__device__ __forceinline__ float bhi(unsigned v) { return __uint_as_float(v & 0xffff0000u); }
__device__ __forceinline__ unsigned short f2b(float f) {
  unsigned u = __float_as_uint(f);
  u += 0x7fffu + ((u >> 16) & 1u);   // RNE (no NaNs in this net)
  return (unsigned short)(u >> 16);
}
__device__ __forceinline__ unsigned packb(float lo, float hi) {
  return (unsigned)f2b(lo) | ((unsigned)f2b(hi) << 16);
}
__device__ __forceinline__ unsigned pk_fp8x4(float a, float b, float c, float d) {
  int r = 0;
  r = __builtin_amdgcn_cvt_pk_fp8_f32(a, b, r, false);
  r = __builtin_amdgcn_cvt_pk_fp8_f32(c, d, r, true);
  return (unsigned)r;
}
__device__ __forceinline__ unsigned char fp8_1(float v) {
  return (unsigned char)(__builtin_amdgcn_cvt_pk_fp8_f32(v, v, 0, false) & 0xff);
}
__device__ __forceinline__ f32x2 upk_fp8(unsigned short s) {
  return __builtin_amdgcn_cvt_pk_f32_fp8((int)s, false);
}

// ---------------- prep: edge binning (phase A) + x->fp8 + 4 weight transposes ----------------

constexpr int EA_BLOCKS  = E / 256;                 // 3125 (exact)
constexpr int XQ_BLOCKS  = (N * IN / 4) / 256;      // 6250 (exact)
constexpr int W1A_BLOCKS = (256 * IN) / 256;        // 128
constexpr int WH_BLOCKS  = (256 * H) / 256;         // 256

__global__ void prep_kernel(const int* __restrict__ srcp, const int* __restrict__ dstp,
                            int* __restrict__ pcount, unsigned* __restrict__ pbuf,
                            const float* __restrict__ x, unsigned* __restrict__ xq,
                            const float* __restrict__ W1a, unsigned short* __restrict__ Wt1a,
                            const float* __restrict__ W1b, unsigned short* __restrict__ Wt1b,
                            const float* __restrict__ W2a, unsigned short* __restrict__ Wt2a,
                            const float* __restrict__ W2b, unsigned short* __restrict__ Wt2b) {
  int b = blockIdx.x;
  int t = threadIdx.x;
  if (b < EA_BLOCKS) {
    // phase A: bin edges into per-XCD per-partition buffers (no cross-XCD line sharing)
    int e = b * 256 + t;
    int d = dstp[e], s = srcp[e];
    int part = d >> 5;
    int slot = ((b & 7) * P) + part;        // blockIdx%8 ~ XCD (locality heuristic only)
    int pos = atomicAdd(&pcount[slot], 1);
    if (pos < CAP) pbuf[(size_t)slot * CAP + pos] = ((unsigned)(d & 31) << 16) | (unsigned)s;
    return;
  }
  b -= EA_BLOCKS;
  if (b < XQ_BLOCKS) {
    int id = b * 256 + t;
    float4 v = ((const float4*)x)[id];
    xq[id] = pk_fp8x4(v.x, v.y, v.z, v.w);
    return;
  }
  b -= XQ_BLOCKS;
  if (b < W1A_BLOCKS) {
    int id = b * 256 + t;               // id = n*128 + k
    int n = id >> 7, k = id & 127;
    Wt1a[id] = f2b(W1a[k * 256 + n]);
    return;
  }
  b -= W1A_BLOCKS;
  const float* Ws;
  unsigned short* Wd;
  if (b < WH_BLOCKS)            { Ws = W1b; Wd = Wt1b; }
  else if (b < 2 * WH_BLOCKS)   { Ws = W2a; Wd = Wt2a; b -= WH_BLOCKS; }
  else                          { Ws = W2b; Wd = Wt2b; b -= 2 * WH_BLOCKS; }
  int id = b * 256 + t;                 // id = n*256 + k
  int n = id >> 8, k = id & 255;
  Wd[id] = f2b(Ws[k * 256 + n]);
}

// ---------------- phase B: drain partition buffers -> bucket CSR + deg ----------------

__global__ __launch_bounds__(256) void csr_kernel(const unsigned* __restrict__ pbuf,
                                                  const int* __restrict__ pcount,
                                                  int* __restrict__ deg, int* __restrict__ csre) {
  __shared__ int ldeg[32];
  int p = blockIdx.x;
  int t = threadIdx.x;
  if (t < 32) ldeg[t] = 0;
  __syncthreads();
  for (int x = 0; x < 8; ++x) {
    int slot = x * P + p;
    int cnt = pcount[slot]; if (cnt > CAP) cnt = CAP;
    const unsigned* seg = pbuf + (size_t)slot * CAP;
    for (int k = t; k < cnt; k += 256) {
      unsigned v = seg[k];
      int dl = v >> 16, s = (int)(v & 0xFFFFu);
      int pos = atomicAdd(&ldeg[dl], 1);
      if (pos < BSTR) csre[((size_t)p * 32 + dl) * BSTR + pos] = s;
    }
  }
  __syncthreads();
  if (t < 32) {
    int node = p * 32 + t;
    if (node < N) deg[node] = min(ldeg[t], BSTR);
  }
}

// ---------------- agg layer 1 (D=128, fp8 table): out_bf16[i] = (1+eps)*in[i] + sum_nbr in[j] ----
// one wave per node; lane loads ushort (2 fp8), 8-deep gather MLP.

__global__ __launch_bounds__(64) void agg1_kernel(const unsigned short* __restrict__ inq,
                                                  const int* __restrict__ deg,
                                                  const int* __restrict__ csre,
                                                  const float* __restrict__ epsp,
                                                  unsigned short* __restrict__ out) {
  int i = blockIdx.x;
  int t = threadIdx.x;
  int dg = deg[i]; if (dg > BSTR) dg = BSTR;
  const int* bkt = csre + (size_t)i * BSTR;
  float sc = 1.0f + epsp[0];
  float a0 = 0.f, a1 = 0.f;
  int j = 0;
  for (; j + 8 <= dg; j += 8) {
    int idx[8];
#pragma unroll
    for (int u = 0; u < 8; ++u) idx[u] = bkt[j + u];
    unsigned short v[8];
#pragma unroll
    for (int u = 0; u < 8; ++u) v[u] = inq[(size_t)idx[u] * 64 + t];
#pragma unroll
    for (int u = 0; u < 8; ++u) { f32x2 w = upk_fp8(v[u]); a0 += w.x; a1 += w.y; }
  }
  for (; j < dg; ++j) {
    f32x2 w = upk_fp8(inq[(size_t)bkt[j] * 64 + t]);
    a0 += w.x; a1 += w.y;
  }
  f32x2 sv = upk_fp8(inq[(size_t)i * 64 + t]);
  a0 += sc * sv.x; a1 += sc * sv.y;
  ((unsigned*)out)[(size_t)i * 64 + t] = packb(a0, a1);
}

// ---------------- agg layer 2 (D=256, fp8 table) split-D: two half-column passes ----------------

__global__ __launch_bounds__(64) void agg2_kernel(const unsigned short* __restrict__ inq,
                                                  const int* __restrict__ deg,
                                                  const int* __restrict__ csre,
                                                  const float* __restrict__ epsp,
                                                  unsigned short* __restrict__ out) {
  int bx = blockIdx.x;
  int half = (bx >= N) ? 1 : 0;
  int i = bx - half * N;
  int t = threadIdx.x;
  int off = half * 64 + t;                      // ushort index within row (row = 128 ushorts)
  int dg = deg[i]; if (dg > BSTR) dg = BSTR;
  const int* bkt = csre + (size_t)i * BSTR;
  float sc = 1.0f + epsp[0];
  float a0 = 0.f, a1 = 0.f;
  int j = 0;
  for (; j + 8 <= dg; j += 8) {
    int idx[8];
#pragma unroll
    for (int u = 0; u < 8; ++u) idx[u] = bkt[j + u];
    unsigned short v[8];
#pragma unroll
    for (int u = 0; u < 8; ++u) v[u] = inq[(size_t)idx[u] * 128 + off];
#pragma unroll
    for (int u = 0; u < 8; ++u) { f32x2 w = upk_fp8(v[u]); a0 += w.x; a1 += w.y; }
  }
  for (; j < dg; ++j) {
    f32x2 w = upk_fp8(inq[(size_t)bkt[j] * 128 + off]);
    a0 += w.x; a1 += w.y;
  }
  f32x2 sv = upk_fp8(inq[(size_t)i * 128 + off]);
  a0 += sc * sv.x; a1 += sc * sv.y;
  ((unsigned*)out)[(size_t)i * 128 + off] = packb(a0, a1);
}

// ---------------- bf16 MFMA GEMM: out[N][256] = act(A[N][K] @ W + b) ----------------
// proven structure: 128x128 tile, BK=32, 4 waves, LDK=40 (0 conflicts). OUT8 -> fp8 output.

template <int K, bool RELU, bool OUT8>
__global__ __launch_bounds__(256, 2) void gemm_bf16_kernel(const unsigned short* __restrict__ A,
                                                           const unsigned short* __restrict__ Bt,
                                                           const float* __restrict__ bias,
                                                           void* __restrict__ outv,
                                                           int Nrows) {
  constexpr int M = 256, LDK = 40;
  __shared__ __align__(16) unsigned short As[128 * LDK];
  __shared__ __align__(16) unsigned short Bs[128 * LDK];
  const int tid  = threadIdx.x;
  const int r0   = blockIdx.x * 128;
  const int c0   = blockIdx.y * 128;
  const int wave = tid >> 6, lane = tid & 63;
  const int quad = lane >> 4, l15 = lane & 15;
  const int wrow = (wave >> 1) * 64, wcol = (wave & 1) * 64;
  const int srow = tid >> 2;
  const int sk8  = (tid & 3) * 8;

  f32x4 acc[4][4];
#pragma unroll
  for (int i = 0; i < 4; ++i)
#pragma unroll
    for (int j = 0; j < 4; ++j) acc[i][j] = (f32x4){0.f, 0.f, 0.f, 0.f};

  for (int k0 = 0; k0 < K; k0 += 32) {
    {
      int row = srow, grow = r0 + row;
      uint4 v = make_uint4(0u, 0u, 0u, 0u);
      if (grow < Nrows) v = *(const uint4*)(A + (size_t)grow * K + k0 + sk8);
      *(uint4*)(As + row * LDK + sk8) = v;
      row += 64; grow = r0 + row;
      uint4 w = make_uint4(0u, 0u, 0u, 0u);
      if (grow < Nrows) w = *(const uint4*)(A + (size_t)grow * K + k0 + sk8);
      *(uint4*)(As + row * LDK + sk8) = w;
      *(uint4*)(Bs + srow * LDK + sk8) =
          *(const uint4*)(Bt + (size_t)(c0 + srow) * K + k0 + sk8);
      *(uint4*)(Bs + (srow + 64) * LDK + sk8) =
          *(const uint4*)(Bt + (size_t)(c0 + srow + 64) * K + k0 + sk8);
    }
    __syncthreads();
    bf16x8 af[4], bfr[4];
#pragma unroll
    for (int mt = 0; mt < 4; ++mt)
      af[mt] = *(const bf16x8*)(As + (wrow + mt * 16 + l15) * LDK + quad * 8);
#pragma unroll
    for (int nt = 0; nt < 4; ++nt)
      bfr[nt] = *(const bf16x8*)(Bs + (wcol + nt * 16 + l15) * LDK + quad * 8);
#pragma unroll
    for (int mt = 0; mt < 4; ++mt)
#pragma unroll
      for (int nt = 0; nt < 4; ++nt)
        acc[mt][nt] = __builtin_amdgcn_mfma_f32_16x16x32_bf16(af[mt], bfr[nt], acc[mt][nt], 0, 0, 0);
    __syncthreads();
  }

  float bv[4];
#pragma unroll
  for (int nt = 0; nt < 4; ++nt) bv[nt] = bias[c0 + wcol + nt * 16 + l15];
#pragma unroll
  for (int mt = 0; mt < 4; ++mt) {
    int gr0 = r0 + wrow + mt * 16 + quad * 4;
#pragma unroll
    for (int i = 0; i < 4; ++i) {
      int grow = gr0 + i;
      if (grow >= Nrows) continue;
#pragma unroll
      for (int nt = 0; nt < 4; ++nt) {
        float v = acc[mt][nt][i] + bv[nt];
        if (RELU) v = fmaxf(v, 0.f);
        int col = c0 + wcol + nt * 16 + l15;
        if (OUT8) ((unsigned char*)outv)[(size_t)grow * M + col] = fp8_1(v);
        else      ((unsigned short*)outv)[(size_t)grow * M + col] = f2b(v);
      }
    }
  }
}

// ---------------- fused mean-pool + classifier + log_softmax ----------------

__global__ __launch_bounds__(128) void pool_final_kernel(const unsigned short* __restrict__ h2,
                                                         const int* __restrict__ batch,
                                                         const float* __restrict__ Wlin,
                                                         const float* __restrict__ blin,
                                                         float* __restrict__ out) {
  __shared__ float sp[H];
  __shared__ float logits[OUT];
  int g = blockIdx.x;
  int t = threadIdx.x;  // 128, 2 cols each
  int lo = 0, hi = N;
  while (lo < hi) { int m = (lo + hi) >> 1; if (batch[m] < g) lo = m + 1; else hi = m; }
  int s = lo;
  lo = 0; hi = N;
  while (lo < hi) { int m = (lo + hi) >> 1; if (batch[m] < g + 1) lo = m + 1; else hi = m; }
  int e = lo;
  float a0 = 0.f, a1 = 0.f;
  const unsigned* base = (const unsigned*)h2;
  int n = s;
  for (; n + 4 <= e; n += 4) {
    unsigned v0 = base[(size_t)(n + 0) * (H / 2) + t];
    unsigned v1 = base[(size_t)(n + 1) * (H / 2) + t];
    unsigned v2 = base[(size_t)(n + 2) * (H / 2) + t];
    unsigned v3 = base[(size_t)(n + 3) * (H / 2) + t];
    a0 += blo(v0) + blo(v1) + blo(v2) + blo(v3);
    a1 += bhi(v0) + bhi(v1) + bhi(v2) + bhi(v3);
  }
  for (; n < e; ++n) {
    unsigned v = base[(size_t)n * (H / 2) + t];
    a0 += blo(v); a1 += bhi(v);
  }
  float inv = 1.0f / fmaxf((float)(e - s), 1.0f);
  sp[2 * t]     = a0 * inv;
  sp[2 * t + 1] = a1 * inv;
  __syncthreads();
  if (t < OUT) {
    float acc = blin[t];
    for (int k = 0; k < H; ++k) acc = fmaf(sp[k], Wlin[k * OUT + t], acc);
    logits[t] = acc;
  }
  __syncthreads();
  if (t == 0) {
    float m = -INFINITY;
    for (int j = 0; j < OUT; ++j) m = fmaxf(m, logits[j]);
    float ssum = 0.f;
    for (int j = 0; j < OUT; ++j) ssum += expf(logits[j] - m);
    float ls = logf(ssum);
    for (int j = 0; j < OUT; ++j) out[(size_t)g * OUT + j] = logits[j] - m - ls;
  }
}

// ---------------- launch ----------------

static inline char* align_up(char* p, size_t a) {
  return (char*)(((uintptr_t)p + a - 1) & ~(a - 1));
}

extern "C" void kernel_launch(void* const* d_in, const int* in_sizes, int n_in,
                              void* d_out, int out_size, void* d_ws, size_t ws_size,
                              hipStream_t stream) {
  const float* x    = (const float*)d_in[0];
  const int*   ei   = (const int*)d_in[1];
  const int*   srcp = ei;
  const int*   dstp = ei + E;
  const int*   batch = (const int*)d_in[2];
  const float* eps1 = (const float*)d_in[3];
  const float* W1a  = (const float*)d_in[4];
  const float* b1a  = (const float*)d_in[5];
  const float* W1b  = (const float*)d_in[6];
  const float* b1b  = (const float*)d_in[7];
  const float* eps2 = (const float*)d_in[8];
  const float* W2a  = (const float*)d_in[9];
  const float* b2a  = (const float*)d_in[10];
  const float* W2b  = (const float*)d_in[11];
  const float* b2b  = (const float*)d_in[12];
  const float* Wlin = (const float*)d_in[13];
  const float* blin = (const float*)d_in[14];
  float* outp = (float*)d_out;

  char* p = (char*)d_ws;
  int* pcount = (int*)p;             p = align_up(p + (size_t)8 * P * 4, 256);
  unsigned* pbuf = (unsigned*)p;     p = align_up(p + (size_t)8 * P * CAP * 4, 256);
  int* deg  = (int*)p;               p = align_up(p + (size_t)N * 4, 256);
  int* csre = (int*)p;               p = align_up(p + (size_t)N * BSTR * 4, 256);
  unsigned* xq = (unsigned*)p;       p = align_up(p + (size_t)N * IN, 256);          // fp8 x
  unsigned char* h1q = (unsigned char*)p;  p = align_up(p + (size_t)N * H, 256);     // fp8 h1
  unsigned short* B1 = (unsigned short*)p; p = align_up(p + (size_t)N * IN * 2, 256);
  unsigned short* B2 = (unsigned short*)p; p = align_up(p + (size_t)N * H * 2, 256);
  unsigned short* B3 = (unsigned short*)p; p = align_up(p + (size_t)N * H * 2, 256);
  unsigned short* Wt1a = (unsigned short*)p;  p = align_up(p + (size_t)H * IN * 2, 256);
  unsigned short* Wt1b = (unsigned short*)p;  p = align_up(p + (size_t)H * H * 2, 256);
  unsigned short* Wt2a = (unsigned short*)p;  p = align_up(p + (size_t)H * H * 2, 256);
  unsigned short* Wt2b = (unsigned short*)p;  p = align_up(p + (size_t)H * H * 2, 256);

  // 0: zero partition counters (tiny)
  hipMemsetAsync(pcount, 0, (size_t)8 * P * 4, stream);

  // 1: prep (edge binning + x->fp8 + weight transposes)
  prep_kernel<<<EA_BLOCKS + XQ_BLOCKS + W1A_BLOCKS + 3 * WH_BLOCKS, 256, 0, stream>>>(
      srcp, dstp, pcount, pbuf, x, xq, W1a, Wt1a, W1b, Wt1b, W2a, Wt2a, W2b, Wt2b);

  // 2: drain bins -> bucket CSR + deg
  csr_kernel<<<P, 256, 0, stream>>>(pbuf, pcount, deg, csre);

  const dim3 ggrid((N + 127) / 128, 2);

  // layer 1
  agg1_kernel<<<N, 64, 0, stream>>>((const unsigned short*)xq, deg, csre, eps1, B1);
  gemm_bf16_kernel<IN, true, false><<<ggrid, 256, 0, stream>>>(B1, Wt1a, b1a, B2, N);
  gemm_bf16_kernel<H, true, true><<<ggrid, 256, 0, stream>>>(B2, Wt1b, b1b, h1q, N);  // h1 -> fp8

  // layer 2
  agg2_kernel<<<2 * N, 64, 0, stream>>>((const unsigned short*)h1q, deg, csre, eps2, B3);
  gemm_bf16_kernel<H, true, false><<<ggrid, 256, 0, stream>>>(B3, Wt2a, b2a, B2, N);
  gemm_bf16_kernel<H, false, false><<<ggrid, 256, 0, stream>>>(B2, Wt2b, b2b, B3, N); // B3 = h2

  // pool + classify
  pool_final_kernel<<<G, 128, 0, stream>>>(B3, batch, Wlin, blin, outp);
}

// Round 10
// 289.223 us; speedup vs baseline: 1.1388x; 1.1052x over previous
//
#include <hip/hip_runtime.h>
#include <math.h>
#include <stdint.h>

constexpr int N   = 50000;
constexpr int E   = 800000;
constexpr int IN  = 128;
constexpr int H   = 256;
constexpr int OUT = 10;
constexpr int G   = 512;
constexpr int BSTR = 64;    // per-node bucket stride
constexpr int P    = (N + 31) / 32;   // 1563 partitions of 32 nodes
constexpr int CAP  = 256;   // per-(xcd,partition) capacity; mean 64, ~24 sigma

typedef __bf16 bf16x8 __attribute__((ext_vector_type(8)));
typedef float  f32x4  __attribute__((ext_vector_type(4)));
typedef float  f32x2  __attribute__((ext_vector_type(2)));

__device__ __forceinline__ float blo(unsigned v) { return __uint_as_float(v << 16); }
__device__ __forceinline__ float bhi(unsigned v) { return __uint_as_float(v & 0xffff0000u); }
__device__ __forceinline__ unsigned short f2b(float f) {
  unsigned u = __float_as_uint(f);
  u += 0x7fffu + ((u >> 16) & 1u);   // RNE (no NaNs in this net)
  return (unsigned short)(u >> 16);
}
__device__ __forceinline__ unsigned packb(float lo, float hi) {
  return (unsigned)f2b(lo) | ((unsigned)f2b(hi) << 16);
}
__device__ __forceinline__ unsigned pk_fp8x4(float a, float b, float c, float d) {
  int r = 0;
  r = __builtin_amdgcn_cvt_pk_fp8_f32(a, b, r, false);
  r = __builtin_amdgcn_cvt_pk_fp8_f32(c, d, r, true);
  return (unsigned)r;
}
__device__ __forceinline__ unsigned char fp8_1(float v) {
  return (unsigned char)(__builtin_amdgcn_cvt_pk_fp8_f32(v, v, 0, false) & 0xff);
}

// ---------------- prep: edge binning (phase A) + x->fp8 + 4 weight transposes ----------------

constexpr int EA_BLOCKS  = E / 256;                 // 3125 (exact)
constexpr int XQ_BLOCKS  = (N * IN / 4) / 256;      // 6250 (exact)
constexpr int W1A_BLOCKS = (256 * IN) / 256;        // 128
constexpr int WH_BLOCKS  = (256 * H) / 256;         // 256

__global__ void prep_kernel(const int* __restrict__ srcp, const int* __restrict__ dstp,
                            int* __restrict__ pcount, unsigned* __restrict__ pbuf,
                            const float* __restrict__ x, unsigned* __restrict__ xq,
                            const float* __restrict__ W1a, unsigned short* __restrict__ Wt1a,
                            const float* __restrict__ W1b, unsigned short* __restrict__ Wt1b,
                            const float* __restrict__ W2a, unsigned short* __restrict__ Wt2a,
                            const float* __restrict__ W2b, unsigned short* __restrict__ Wt2b) {
  int b = blockIdx.x;
  int t = threadIdx.x;
  if (b < EA_BLOCKS) {
    // phase A: bin edges into per-XCD per-partition buffers (no cross-XCD line sharing)
    int e = b * 256 + t;
    int d = dstp[e], s = srcp[e];
    int part = d >> 5;
    int slot = ((b & 7) * P) + part;        // blockIdx%8 ~ XCD (locality heuristic only)
    int pos = atomicAdd(&pcount[slot], 1);
    if (pos < CAP) pbuf[(size_t)slot * CAP + pos] = ((unsigned)(d & 31) << 16) | (unsigned)s;
    return;
  }
  b -= EA_BLOCKS;
  if (b < XQ_BLOCKS) {
    int id = b * 256 + t;
    float4 v = ((const float4*)x)[id];
    xq[id] = pk_fp8x4(v.x, v.y, v.z, v.w);
    return;
  }
  b -= XQ_BLOCKS;
  if (b < W1A_BLOCKS) {
    int id = b * 256 + t;               // id = n*128 + k
    int n = id >> 7, k = id & 127;
    Wt1a[id] = f2b(W1a[k * 256 + n]);
    return;
  }
  b -= W1A_BLOCKS;
  const float* Ws;
  unsigned short* Wd;
  if (b < WH_BLOCKS)            { Ws = W1b; Wd = Wt1b; }
  else if (b < 2 * WH_BLOCKS)   { Ws = W2a; Wd = Wt2a; b -= WH_BLOCKS; }
  else                          { Ws = W2b; Wd = Wt2b; b -= 2 * WH_BLOCKS; }
  int id = b * 256 + t;                 // id = n*256 + k
  int n = id >> 8, k = id & 255;
  Wd[id] = f2b(Ws[k * 256 + n]);
}

// ---------------- phase B: drain partition buffers -> bucket CSR + deg ----------------

__global__ __launch_bounds__(256) void csr_kernel(const unsigned* __restrict__ pbuf,
                                                  const int* __restrict__ pcount,
                                                  int* __restrict__ deg, int* __restrict__ csre) {
  __shared__ int ldeg[32];
  int p = blockIdx.x;
  int t = threadIdx.x;
  if (t < 32) ldeg[t] = 0;
  __syncthreads();
  for (int x = 0; x < 8; ++x) {
    int slot = x * P + p;
    int cnt = pcount[slot]; if (cnt > CAP) cnt = CAP;
    const unsigned* seg = pbuf + (size_t)slot * CAP;
    for (int k = t; k < cnt; k += 256) {
      unsigned v = seg[k];
      int dl = v >> 16, s = (int)(v & 0xFFFFu);
      int pos = atomicAdd(&ldeg[dl], 1);
      if (pos < BSTR) csre[((size_t)p * 32 + dl) * BSTR + pos] = s;
    }
  }
  __syncthreads();
  if (t < 32) {
    int node = p * 32 + t;
    if (node < N) deg[node] = min(ldeg[t], BSTR);
  }
}

// ---------------- paired-node fp8 gather aggregation ----------------
// out_bf16[i] = (1+eps)*in[i] + sum_nbr in[j].
// One wave serves TWO nodes: lanes 0-31 node 2p, lanes 32-63 node 2p+1; each lane
// loads 4 B -> one gather instruction moves 256 B (2 edge-halves). Single predicated
// loop to pairwise dgmax (index-clamped; padded gathers zero-weighted).
// RS=128 (agg1, grid N/2) or RS=256 (agg2 split-D, grid N: pair-major, half = bx/(N/2)).

template <int RS>
__global__ __launch_bounds__(64) void agg_pair_kernel(
    const unsigned char* __restrict__ inq,
    const int* __restrict__ deg, const int* __restrict__ csre,
    const float* __restrict__ epsp, unsigned short* __restrict__ out) {
  constexpr int NPAIR = N / 2;
  int bx = blockIdx.x;
  int half = (RS == 256) ? (bx / NPAIR) : 0;
  int pair = (RS == 256) ? (bx - half * NPAIR) : bx;
  int lane = threadIdx.x;
  int hsel = lane >> 5;               // which node of the pair
  int l = lane & 31;
  int i = pair * 2 + hsel;
  int dg = deg[i]; if (dg > BSTR) dg = BSTR;
  const int* bkt = csre + (size_t)i * BSTR;
  int dgmax = max(dg, __shfl_xor(dg, 32));   // max across the two halves
  const unsigned char* rowbase = inq + half * 128 + l * 4;
  float a0 = 0.f, a1 = 0.f, a2 = 0.f, a3 = 0.f;
  int hi_j = dg - 1; if (hi_j < 0) hi_j = 0;
  for (int j = 0; j < dgmax; j += 8) {
    unsigned idx[8], v[8];
#pragma unroll
    for (int u = 0; u < 8; ++u) {
      int jc = j + u; if (jc > hi_j) jc = hi_j;
      unsigned raw = (unsigned)bkt[jc];
      idx[u] = raw < (unsigned)N ? raw : 0u;      // poison-safe
    }
#pragma unroll
    for (int u = 0; u < 8; ++u) v[u] = *(const unsigned*)(rowbase + (size_t)idx[u] * RS);
#pragma unroll
    for (int u = 0; u < 8; ++u) {
      float s = (j + u < dg) ? 1.f : 0.f;
      f32x2 lo = __builtin_amdgcn_cvt_pk_f32_fp8((int)v[u], false);
      f32x2 hh = __builtin_amdgcn_cvt_pk_f32_fp8((int)v[u], true);
      a0 += s * lo.x; a1 += s * lo.y; a2 += s * hh.x; a3 += s * hh.y;
    }
  }
  float sc = 1.0f + epsp[0];
  unsigned sv = *(const unsigned*)(rowbase + (size_t)i * RS);
  f32x2 slo = __builtin_amdgcn_cvt_pk_f32_fp8((int)sv, false);
  f32x2 shi = __builtin_amdgcn_cvt_pk_f32_fp8((int)sv, true);
  a0 += sc * slo.x; a1 += sc * slo.y; a2 += sc * shi.x; a3 += sc * shi.y;
  unsigned short* orow = out + (size_t)i * RS + half * 128 + l * 4;
  *(uint2*)orow = make_uint2(packb(a0, a1), packb(a2, a3));
}

// ---------------- bf16 MFMA GEMM: out[N][256] = act(A[N][K] @ W + b) ----------------
// Merged-column version: one block = 128 rows x ALL 256 cols (A fetched once).
// BK=32, 4 waves, LDK=40 (proven 0-conflict). acc[2][4][4]. OUT8 -> fp8 output.

template <int K, bool RELU, bool OUT8>
__global__ __launch_bounds__(256, 2) void gemm_bf16_kernel(const unsigned short* __restrict__ A,
                                                           const unsigned short* __restrict__ Bt,
                                                           const float* __restrict__ bias,
                                                           void* __restrict__ outv,
                                                           int Nrows) {
  constexpr int M = 256, LDK = 40;
  __shared__ __align__(16) unsigned short As[128 * LDK];
  __shared__ __align__(16) unsigned short Bs[256 * LDK];
  const int tid  = threadIdx.x;
  const int r0   = blockIdx.x * 128;
  const int wave = tid >> 6, lane = tid & 63;
  const int quad = lane >> 4, l15 = lane & 15;
  const int wrow = (wave >> 1) * 64, wcol = (wave & 1) * 64;
  const int srow = tid >> 2;
  const int sk8  = (tid & 3) * 8;

  f32x4 acc[2][4][4];
#pragma unroll
  for (int c = 0; c < 2; ++c)
#pragma unroll
    for (int i = 0; i < 4; ++i)
#pragma unroll
      for (int j = 0; j < 4; ++j) acc[c][i][j] = (f32x4){0.f, 0.f, 0.f, 0.f};

  for (int k0 = 0; k0 < K; k0 += 32) {
    {
      int grow = r0 + srow;
      uint4 v = make_uint4(0u, 0u, 0u, 0u);
      if (grow < Nrows) v = *(const uint4*)(A + (size_t)grow * K + k0 + sk8);
      *(uint4*)(As + srow * LDK + sk8) = v;
      grow = r0 + srow + 64;
      uint4 w = make_uint4(0u, 0u, 0u, 0u);
      if (grow < Nrows) w = *(const uint4*)(A + (size_t)grow * K + k0 + sk8);
      *(uint4*)(As + (srow + 64) * LDK + sk8) = w;
#pragma unroll
      for (int sgm = 0; sgm < 4; ++sgm) {
        int col = srow + sgm * 64;
        *(uint4*)(Bs + col * LDK + sk8) = *(const uint4*)(Bt + (size_t)col * K + k0 + sk8);
      }
    }
    __syncthreads();
    bf16x8 af[4];
#pragma unroll
    for (int mt = 0; mt < 4; ++mt)
      af[mt] = *(const bf16x8*)(As + (wrow + mt * 16 + l15) * LDK + quad * 8);
#pragma unroll
    for (int ch = 0; ch < 2; ++ch) {
      bf16x8 bfr[4];
#pragma unroll
      for (int nt = 0; nt < 4; ++nt)
        bfr[nt] = *(const bf16x8*)(Bs + (ch * 128 + wcol + nt * 16 + l15) * LDK + quad * 8);
#pragma unroll
      for (int mt = 0; mt < 4; ++mt)
#pragma unroll
        for (int nt = 0; nt < 4; ++nt)
          acc[ch][mt][nt] =
              __builtin_amdgcn_mfma_f32_16x16x32_bf16(af[mt], bfr[nt], acc[ch][mt][nt], 0, 0, 0);
    }
    __syncthreads();
  }

#pragma unroll
  for (int ch = 0; ch < 2; ++ch) {
    float bv[4];
#pragma unroll
    for (int nt = 0; nt < 4; ++nt) bv[nt] = bias[ch * 128 + wcol + nt * 16 + l15];
#pragma unroll
    for (int mt = 0; mt < 4; ++mt) {
      int gr0 = r0 + wrow + mt * 16 + quad * 4;
#pragma unroll
      for (int i = 0; i < 4; ++i) {
        int grow = gr0 + i;
        if (grow >= Nrows) continue;
#pragma unroll
        for (int nt = 0; nt < 4; ++nt) {
          float v = acc[ch][mt][nt][i] + bv[nt];
          if (RELU) v = fmaxf(v, 0.f);
          int col = ch * 128 + wcol + nt * 16 + l15;
          if (OUT8) ((unsigned char*)outv)[(size_t)grow * M + col] = fp8_1(v);
          else      ((unsigned short*)outv)[(size_t)grow * M + col] = f2b(v);
        }
      }
    }
  }
}

// ---------------- fused mean-pool + classifier + log_softmax ----------------

__global__ __launch_bounds__(128) void pool_final_kernel(const unsigned short* __restrict__ h2,
                                                         const int* __restrict__ batch,
                                                         const float* __restrict__ Wlin,
                                                         const float* __restrict__ blin,
                                                         float* __restrict__ out) {
  __shared__ float sp[H];
  __shared__ float logits[OUT];
  int g = blockIdx.x;
  int t = threadIdx.x;  // 128, 2 cols each
  int lo = 0, hi = N;
  while (lo < hi) { int m = (lo + hi) >> 1; if (batch[m] < g) lo = m + 1; else hi = m; }
  int s = lo;
  lo = 0; hi = N;
  while (lo < hi) { int m = (lo + hi) >> 1; if (batch[m] < g + 1) lo = m + 1; else hi = m; }
  int e = lo;
  float a0 = 0.f, a1 = 0.f;
  const unsigned* base = (const unsigned*)h2;
  int n = s;
  for (; n + 4 <= e; n += 4) {
    unsigned v0 = base[(size_t)(n + 0) * (H / 2) + t];
    unsigned v1 = base[(size_t)(n + 1) * (H / 2) + t];
    unsigned v2 = base[(size_t)(n + 2) * (H / 2) + t];
    unsigned v3 = base[(size_t)(n + 3) * (H / 2) + t];
    a0 += blo(v0) + blo(v1) + blo(v2) + blo(v3);
    a1 += bhi(v0) + bhi(v1) + bhi(v2) + bhi(v3);
  }
  for (; n < e; ++n) {
    unsigned v = base[(size_t)n * (H / 2) + t];
    a0 += blo(v); a1 += bhi(v);
  }
  float inv = 1.0f / fmaxf((float)(e - s), 1.0f);
  sp[2 * t]     = a0 * inv;
  sp[2 * t + 1] = a1 * inv;
  __syncthreads();
  if (t < OUT) {
    float acc = blin[t];
    for (int k = 0; k < H; ++k) acc = fmaf(sp[k], Wlin[k * OUT + t], acc);
    logits[t] = acc;
  }
  __syncthreads();
  if (t == 0) {
    float m = -INFINITY;
    for (int j = 0; j < OUT; ++j) m = fmaxf(m, logits[j]);
    float ssum = 0.f;
    for (int j = 0; j < OUT; ++j) ssum += expf(logits[j] - m);
    float ls = logf(ssum);
    for (int j = 0; j < OUT; ++j) out[(size_t)g * OUT + j] = logits[j] - m - ls;
  }
}

// ---------------- launch ----------------

static inline char* align_up(char* p, size_t a) {
  return (char*)(((uintptr_t)p + a - 1) & ~(a - 1));
}

extern "C" void kernel_launch(void* const* d_in, const int* in_sizes, int n_in,
                              void* d_out, int out_size, void* d_ws, size_t ws_size,
                              hipStream_t stream) {
  const float* x    = (const float*)d_in[0];
  const int*   ei   = (const int*)d_in[1];
  const int*   srcp = ei;
  const int*   dstp = ei + E;
  const int*   batch = (const int*)d_in[2];
  const float* eps1 = (const float*)d_in[3];
  const float* W1a  = (const float*)d_in[4];
  const float* b1a  = (const float*)d_in[5];
  const float* W1b  = (const float*)d_in[6];
  const float* b1b  = (const float*)d_in[7];
  const float* eps2 = (const float*)d_in[8];
  const float* W2a  = (const float*)d_in[9];
  const float* b2a  = (const float*)d_in[10];
  const float* W2b  = (const float*)d_in[11];
  const float* b2b  = (const float*)d_in[12];
  const float* Wlin = (const float*)d_in[13];
  const float* blin = (const float*)d_in[14];
  float* outp = (float*)d_out;

  char* p = (char*)d_ws;
  int* pcount = (int*)p;             p = align_up(p + (size_t)8 * P * 4, 256);
  unsigned* pbuf = (unsigned*)p;     p = align_up(p + (size_t)8 * P * CAP * 4, 256);
  int* deg  = (int*)p;               p = align_up(p + (size_t)N * 4, 256);
  int* csre = (int*)p;               p = align_up(p + (size_t)N * BSTR * 4, 256);
  unsigned* xq = (unsigned*)p;       p = align_up(p + (size_t)N * IN, 256);          // fp8 x
  unsigned char* h1q = (unsigned char*)p;  p = align_up(p + (size_t)N * H, 256);     // fp8 h1
  unsigned short* B1 = (unsigned short*)p; p = align_up(p + (size_t)N * IN * 2, 256);
  unsigned short* B2 = (unsigned short*)p; p = align_up(p + (size_t)N * H * 2, 256);
  unsigned short* B3 = (unsigned short*)p; p = align_up(p + (size_t)N * H * 2, 256);
  unsigned short* Wt1a = (unsigned short*)p;  p = align_up(p + (size_t)H * IN * 2, 256);
  unsigned short* Wt1b = (unsigned short*)p;  p = align_up(p + (size_t)H * H * 2, 256);
  unsigned short* Wt2a = (unsigned short*)p;  p = align_up(p + (size_t)H * H * 2, 256);
  unsigned short* Wt2b = (unsigned short*)p;  p = align_up(p + (size_t)H * H * 2, 256);

  // 0: zero partition counters (tiny)
  hipMemsetAsync(pcount, 0, (size_t)8 * P * 4, stream);

  // 1: prep (edge binning + x->fp8 + weight transposes)
  prep_kernel<<<EA_BLOCKS + XQ_BLOCKS + W1A_BLOCKS + 3 * WH_BLOCKS, 256, 0, stream>>>(
      srcp, dstp, pcount, pbuf, x, xq, W1a, Wt1a, W1b, Wt1b, W2a, Wt2a, W2b, Wt2b);

  // 2: drain bins -> bucket CSR + deg
  csr_kernel<<<P, 256, 0, stream>>>(pbuf, pcount, deg, csre);

  const int ggrid = (N + 127) / 128;   // 391

  // layer 1
  agg_pair_kernel<IN><<<N / 2, 64, 0, stream>>>((const unsigned char*)xq, deg, csre, eps1, B1);
  gemm_bf16_kernel<IN, true, false><<<ggrid, 256, 0, stream>>>(B1, Wt1a, b1a, B2, N);
  gemm_bf16_kernel<H, true, true><<<ggrid, 256, 0, stream>>>(B2, Wt1b, b1b, h1q, N);  // h1 -> fp8

  // layer 2
  agg_pair_kernel<H><<<N, 64, 0, stream>>>(h1q, deg, csre, eps2, B3);
  gemm_bf16_kernel<H, true, false><<<ggrid, 256, 0, stream>>>(B3, Wt2a, b2a, B2, N);
  gemm_bf16_kernel<H, false, false><<<ggrid, 256, 0, stream>>>(B2, Wt2b, b2b, B3, N); // B3 = h2

  // pool + classify
  pool_final_kernel<<<G, 128, 0, stream>>>(B3, batch, Wlin, blin, outp);
}

// Round 11
// 262.531 us; speedup vs baseline: 1.2546x; 1.1017x over previous
//
#include <hip/hip_runtime.h>
#include <math.h>
#include <stdint.h>

constexpr int N   = 50000;
constexpr int E   = 800000;
constexpr int IN  = 128;
constexpr int H   = 256;
constexpr int OUT = 10;
constexpr int G   = 512;
constexpr int BSTR = 64;    // per-node bucket stride

// deterministic binning geometry
constexpr int NPART  = 391;   // partitions of 128 nodes (d>>7), covers 50047 >= N-1
constexpr int SEGCAP = 48;    // entries per (part, block) segment = 192 B = 3 lines exactly
constexpr int EPB    = 4096;  // edges per phase-A block
constexpr int AB     = (E + EPB - 1) / EPB;   // 196 phase-A blocks

typedef __bf16 bf16x8 __attribute__((ext_vector_type(8)));
typedef float  f32x4  __attribute__((ext_vector_type(4)));
typedef float  f32x2  __attribute__((ext_vector_type(2)));

__device__ __forceinline__ float blo(unsigned v) { return __uint_as_float(v << 16); }
__device__ __forceinline__ float bhi(unsigned v) { return __uint_as_float(v & 0xffff0000u); }
__device__ __forceinline__ unsigned short f2b(float f) {
  unsigned u = __float_as_uint(f);
  u += 0x7fffu + ((u >> 16) & 1u);   // RNE (no NaNs in this net)
  return (unsigned short)(u >> 16);
}
__device__ __forceinline__ unsigned packb(float lo, float hi) {
  return (unsigned)f2b(lo) | ((unsigned)f2b(hi) << 16);
}
__device__ __forceinline__ unsigned pk_fp8x4(float a, float b, float c, float d) {
  int r = 0;
  r = __builtin_amdgcn_cvt_pk_fp8_f32(a, b, r, false);
  r = __builtin_amdgcn_cvt_pk_fp8_f32(c, d, r, true);
  return (unsigned)r;
}
__device__ __forceinline__ unsigned char fp8_1(float v) {
  return (unsigned char)(__builtin_amdgcn_cvt_pk_fp8_f32(v, v, 0, false) & 0xff);
}

// ---------------- prep: phase-A edge binning (LDS sort, 0 global atomics) + x->fp8 + W^T ----------------

constexpr int XQ_BLOCKS  = (N * IN / 4) / 256;      // 6250 (exact)
constexpr int W1A_BLOCKS = (256 * IN) / 256;        // 128
constexpr int WH_BLOCKS  = (256 * H) / 256;         // 256

__global__ __launch_bounds__(256) void prep_kernel(
    const int* __restrict__ srcp, const int* __restrict__ dstp,
    unsigned* __restrict__ pbuf, int* __restrict__ pcnt,
    const float* __restrict__ x, unsigned* __restrict__ xq,
    const float* __restrict__ W1a, unsigned short* __restrict__ Wt1a,
    const float* __restrict__ W1b, unsigned short* __restrict__ Wt1b,
    const float* __restrict__ W2a, unsigned short* __restrict__ Wt2a,
    const float* __restrict__ W2b, unsigned short* __restrict__ Wt2b) {
  __shared__ int lcur[NPART];
  int b = blockIdx.x;
  int t = threadIdx.x;
  if (b < AB) {
    // phase A: LDS counting-append of up to EPB edges into block-private segments
    for (int j = t; j < NPART; j += 256) lcur[j] = 0;
    __syncthreads();
    const int e0 = b * EPB;
#pragma unroll
    for (int r = 0; r < EPB / 1024; ++r) {          // 4 rounds x 4 edges/thread
      int base = e0 + (r * 256 + t) * 4;
      if (base < E) {                               // base%4==0 and E%4==0 -> base+3 < E
        int4 d4 = *(const int4*)(dstp + base);
        int4 s4 = *(const int4*)(srcp + base);
        int dd[4] = {d4.x, d4.y, d4.z, d4.w};
        int ss[4] = {s4.x, s4.y, s4.z, s4.w};
#pragma unroll
        for (int u = 0; u < 4; ++u) {
          int part = dd[u] >> 7, dl = dd[u] & 127;
          int pos = atomicAdd(&lcur[part], 1);      // LDS atomic
          if (pos < SEGCAP)
            pbuf[((size_t)part * AB + b) * SEGCAP + pos] =
                ((unsigned)dl << 16) | (unsigned)ss[u];
        }
      }
    }
    __syncthreads();
    for (int j = t; j < NPART; j += 256) pcnt[b * NPART + j] = min(lcur[j], SEGCAP);
    return;
  }
  b -= AB;
  if (b < XQ_BLOCKS) {
    int id = b * 256 + t;
    float4 v = ((const float4*)x)[id];
    xq[id] = pk_fp8x4(v.x, v.y, v.z, v.w);
    return;
  }
  b -= XQ_BLOCKS;
  if (b < W1A_BLOCKS) {
    int id = b * 256 + t;               // id = n*128 + k
    int n = id >> 7, k = id & 127;
    Wt1a[id] = f2b(W1a[k * 256 + n]);
    return;
  }
  b -= W1A_BLOCKS;
  const float* Ws;
  unsigned short* Wd;
  if (b < WH_BLOCKS)            { Ws = W1b; Wd = Wt1b; }
  else if (b < 2 * WH_BLOCKS)   { Ws = W2a; Wd = Wt2a; b -= WH_BLOCKS; }
  else                          { Ws = W2b; Wd = Wt2b; b -= 2 * WH_BLOCKS; }
  int id = b * 256 + t;                 // id = n*256 + k
  int n = id >> 8, k = id & 255;
  Wd[id] = f2b(Ws[k * 256 + n]);
}

// ---------------- phase B: drain partition segments -> bucket CSR + deg ----------------
// block p: prefix-scan the 196 segment counts, flat-iterate entries (binary search),
// LDS-atomic per-node rank, scatter into block-private [128 node][64] window.

__global__ __launch_bounds__(256) void csr_kernel(const unsigned* __restrict__ pbuf,
                                                  const int* __restrict__ pcnt,
                                                  int* __restrict__ deg, int* __restrict__ csre) {
  __shared__ int sa[256], sb[256];
  __shared__ int ldeg[128];
  int p = blockIdx.x;     // 0..NPART-1
  int t = threadIdx.x;
  if (t < 128) ldeg[t] = 0;
  sa[t] = (t < AB) ? pcnt[t * NPART + p] : 0;
  __syncthreads();
  int* cur = sa; int* nxt = sb;
#pragma unroll
  for (int off = 1; off < 256; off <<= 1) {
    nxt[t] = cur[t] + ((t >= off) ? cur[t - off] : 0);
    __syncthreads();
    int* tmp = cur; cur = nxt; nxt = tmp;
  }
  // cur = inclusive scan of counts
  int T = cur[255];
  const unsigned* seg = pbuf + (size_t)p * AB * SEGCAP;
  for (int f = t; f < T; f += 256) {
    int lo = 0, hi = AB - 1;
    while (lo < hi) { int m = (lo + hi) >> 1; if (cur[m] > f) hi = m; else lo = m + 1; }
    int bb = lo;
    int excl = bb ? cur[bb - 1] : 0;
    unsigned v = seg[(size_t)bb * SEGCAP + (f - excl)];
    int dl = (int)(v >> 16), s = (int)(v & 0xFFFFu);
    int pos = atomicAdd(&ldeg[dl], 1);
    if (pos < BSTR) csre[(((size_t)p << 7) + dl) * BSTR + pos] = s;
  }
  __syncthreads();
  if (t < 128) {
    int node = (p << 7) + t;
    if (node < N) deg[node] = min(ldeg[t], BSTR);
  }
}

// ---------------- paired-node fp8 gather aggregation (proven r10 structure) ----------------

template <int RS>
__global__ __launch_bounds__(64) void agg_pair_kernel(
    const unsigned char* __restrict__ inq,
    const int* __restrict__ deg, const int* __restrict__ csre,
    const float* __restrict__ epsp, unsigned short* __restrict__ out) {
  constexpr int NPAIR = N / 2;
  int bx = blockIdx.x;
  int half = (RS == 256) ? (bx / NPAIR) : 0;
  int pair = (RS == 256) ? (bx - half * NPAIR) : bx;
  int lane = threadIdx.x;
  int hsel = lane >> 5;               // which node of the pair
  int l = lane & 31;
  int i = pair * 2 + hsel;
  int dg = deg[i]; if (dg > BSTR) dg = BSTR;
  const int* bkt = csre + (size_t)i * BSTR;
  int dgmax = max(dg, __shfl_xor(dg, 32));   // max across the two halves
  const unsigned char* rowbase = inq + half * 128 + l * 4;
  float a0 = 0.f, a1 = 0.f, a2 = 0.f, a3 = 0.f;
  int hi_j = dg - 1; if (hi_j < 0) hi_j = 0;
  for (int j = 0; j < dgmax; j += 8) {
    unsigned idx[8], v[8];
#pragma unroll
    for (int u = 0; u < 8; ++u) {
      int jc = j + u; if (jc > hi_j) jc = hi_j;
      unsigned raw = (unsigned)bkt[jc];
      idx[u] = raw < (unsigned)N ? raw : 0u;      // poison-safe
    }
#pragma unroll
    for (int u = 0; u < 8; ++u) v[u] = *(const unsigned*)(rowbase + (size_t)idx[u] * RS);
#pragma unroll
    for (int u = 0; u < 8; ++u) {
      float s = (j + u < dg) ? 1.f : 0.f;
      f32x2 lo = __builtin_amdgcn_cvt_pk_f32_fp8((int)v[u], false);
      f32x2 hh = __builtin_amdgcn_cvt_pk_f32_fp8((int)v[u], true);
      a0 += s * lo.x; a1 += s * lo.y; a2 += s * hh.x; a3 += s * hh.y;
    }
  }
  float sc = 1.0f + epsp[0];
  unsigned sv = *(const unsigned*)(rowbase + (size_t)i * RS);
  f32x2 slo = __builtin_amdgcn_cvt_pk_f32_fp8((int)sv, false);
  f32x2 shi = __builtin_amdgcn_cvt_pk_f32_fp8((int)sv, true);
  a0 += sc * slo.x; a1 += sc * slo.y; a2 += sc * shi.x; a3 += sc * shi.y;
  unsigned short* orow = out + (size_t)i * RS + half * 128 + l * 4;
  *(uint2*)orow = make_uint2(packb(a0, a1), packb(a2, a3));
}

// ---------------- bf16 MFMA GEMM: merged-column (128 rows x 256 cols), BK=32 ----------------

template <int K, bool RELU, bool OUT8>
__global__ __launch_bounds__(256, 2) void gemm_bf16_kernel(const unsigned short* __restrict__ A,
                                                           const unsigned short* __restrict__ Bt,
                                                           const float* __restrict__ bias,
                                                           void* __restrict__ outv,
                                                           int Nrows) {
  constexpr int M = 256, LDK = 40;
  __shared__ __align__(16) unsigned short As[128 * LDK];
  __shared__ __align__(16) unsigned short Bs[256 * LDK];
  const int tid  = threadIdx.x;
  const int r0   = blockIdx.x * 128;
  const int wave = tid >> 6, lane = tid & 63;
  const int quad = lane >> 4, l15 = lane & 15;
  const int wrow = (wave >> 1) * 64, wcol = (wave & 1) * 64;
  const int srow = tid >> 2;
  const int sk8  = (tid & 3) * 8;

  f32x4 acc[2][4][4];
#pragma unroll
  for (int c = 0; c < 2; ++c)
#pragma unroll
    for (int i = 0; i < 4; ++i)
#pragma unroll
      for (int j = 0; j < 4; ++j) acc[c][i][j] = (f32x4){0.f, 0.f, 0.f, 0.f};

  for (int k0 = 0; k0 < K; k0 += 32) {
    {
      int grow = r0 + srow;
      uint4 v = make_uint4(0u, 0u, 0u, 0u);
      if (grow < Nrows) v = *(const uint4*)(A + (size_t)grow * K + k0 + sk8);
      *(uint4*)(As + srow * LDK + sk8) = v;
      grow = r0 + srow + 64;
      uint4 w = make_uint4(0u, 0u, 0u, 0u);
      if (grow < Nrows) w = *(const uint4*)(A + (size_t)grow * K + k0 + sk8);
      *(uint4*)(As + (srow + 64) * LDK + sk8) = w;
#pragma unroll
      for (int sgm = 0; sgm < 4; ++sgm) {
        int col = srow + sgm * 64;
        *(uint4*)(Bs + col * LDK + sk8) = *(const uint4*)(Bt + (size_t)col * K + k0 + sk8);
      }
    }
    __syncthreads();
    bf16x8 af[4];
#pragma unroll
    for (int mt = 0; mt < 4; ++mt)
      af[mt] = *(const bf16x8*)(As + (wrow + mt * 16 + l15) * LDK + quad * 8);
#pragma unroll
    for (int ch = 0; ch < 2; ++ch) {
      bf16x8 bfr[4];
#pragma unroll
      for (int nt = 0; nt < 4; ++nt)
        bfr[nt] = *(const bf16x8*)(Bs + (ch * 128 + wcol + nt * 16 + l15) * LDK + quad * 8);
#pragma unroll
      for (int mt = 0; mt < 4; ++mt)
#pragma unroll
        for (int nt = 0; nt < 4; ++nt)
          acc[ch][mt][nt] =
              __builtin_amdgcn_mfma_f32_16x16x32_bf16(af[mt], bfr[nt], acc[ch][mt][nt], 0, 0, 0);
    }
    __syncthreads();
  }

#pragma unroll
  for (int ch = 0; ch < 2; ++ch) {
    float bv[4];
#pragma unroll
    for (int nt = 0; nt < 4; ++nt) bv[nt] = bias[ch * 128 + wcol + nt * 16 + l15];
#pragma unroll
    for (int mt = 0; mt < 4; ++mt) {
      int gr0 = r0 + wrow + mt * 16 + quad * 4;
#pragma unroll
      for (int i = 0; i < 4; ++i) {
        int grow = gr0 + i;
        if (grow >= Nrows) continue;
#pragma unroll
        for (int nt = 0; nt < 4; ++nt) {
          float v = acc[ch][mt][nt][i] + bv[nt];
          if (RELU) v = fmaxf(v, 0.f);
          int col = ch * 128 + wcol + nt * 16 + l15;
          if (OUT8) ((unsigned char*)outv)[(size_t)grow * M + col] = fp8_1(v);
          else      ((unsigned short*)outv)[(size_t)grow * M + col] = f2b(v);
        }
      }
    }
  }
}

// ---------------- fused mean-pool + classifier + log_softmax ----------------

__global__ __launch_bounds__(128) void pool_final_kernel(const unsigned short* __restrict__ h2,
                                                         const int* __restrict__ batch,
                                                         const float* __restrict__ Wlin,
                                                         const float* __restrict__ blin,
                                                         float* __restrict__ out) {
  __shared__ float sp[H];
  __shared__ float logits[OUT];
  int g = blockIdx.x;
  int t = threadIdx.x;  // 128, 2 cols each
  int lo = 0, hi = N;
  while (lo < hi) { int m = (lo + hi) >> 1; if (batch[m] < g) lo = m + 1; else hi = m; }
  int s = lo;
  lo = 0; hi = N;
  while (lo < hi) { int m = (lo + hi) >> 1; if (batch[m] < g + 1) lo = m + 1; else hi = m; }
  int e = lo;
  float a0 = 0.f, a1 = 0.f;
  const unsigned* base = (const unsigned*)h2;
  int n = s;
  for (; n + 4 <= e; n += 4) {
    unsigned v0 = base[(size_t)(n + 0) * (H / 2) + t];
    unsigned v1 = base[(size_t)(n + 1) * (H / 2) + t];
    unsigned v2 = base[(size_t)(n + 2) * (H / 2) + t];
    unsigned v3 = base[(size_t)(n + 3) * (H / 2) + t];
    a0 += blo(v0) + blo(v1) + blo(v2) + blo(v3);
    a1 += bhi(v0) + bhi(v1) + bhi(v2) + bhi(v3);
  }
  for (; n < e; ++n) {
    unsigned v = base[(size_t)n * (H / 2) + t];
    a0 += blo(v); a1 += bhi(v);
  }
  float inv = 1.0f / fmaxf((float)(e - s), 1.0f);
  sp[2 * t]     = a0 * inv;
  sp[2 * t + 1] = a1 * inv;
  __syncthreads();
  if (t < OUT) {
    float acc = blin[t];
    for (int k = 0; k < H; ++k) acc = fmaf(sp[k], Wlin[k * OUT + t], acc);
    logits[t] = acc;
  }
  __syncthreads();
  if (t == 0) {
    float m = -INFINITY;
    for (int j = 0; j < OUT; ++j) m = fmaxf(m, logits[j]);
    float ssum = 0.f;
    for (int j = 0; j < OUT; ++j) ssum += expf(logits[j] - m);
    float ls = logf(ssum);
    for (int j = 0; j < OUT; ++j) out[(size_t)g * OUT + j] = logits[j] - m - ls;
  }
}

// ---------------- launch ----------------

static inline char* align_up(char* p, size_t a) {
  return (char*)(((uintptr_t)p + a - 1) & ~(a - 1));
}

extern "C" void kernel_launch(void* const* d_in, const int* in_sizes, int n_in,
                              void* d_out, int out_size, void* d_ws, size_t ws_size,
                              hipStream_t stream) {
  const float* x    = (const float*)d_in[0];
  const int*   ei   = (const int*)d_in[1];
  const int*   srcp = ei;
  const int*   dstp = ei + E;
  const int*   batch = (const int*)d_in[2];
  const float* eps1 = (const float*)d_in[3];
  const float* W1a  = (const float*)d_in[4];
  const float* b1a  = (const float*)d_in[5];
  const float* W1b  = (const float*)d_in[6];
  const float* b1b  = (const float*)d_in[7];
  const float* eps2 = (const float*)d_in[8];
  const float* W2a  = (const float*)d_in[9];
  const float* b2a  = (const float*)d_in[10];
  const float* W2b  = (const float*)d_in[11];
  const float* b2b  = (const float*)d_in[12];
  const float* Wlin = (const float*)d_in[13];
  const float* blin = (const float*)d_in[14];
  float* outp = (float*)d_out;

  char* p = (char*)d_ws;
  unsigned* pbuf = (unsigned*)p;     p = align_up(p + (size_t)NPART * AB * SEGCAP * 4, 256);
  int* pcnt = (int*)p;               p = align_up(p + (size_t)AB * NPART * 4, 256);
  int* deg  = (int*)p;               p = align_up(p + (size_t)N * 4, 256);
  int* csre = (int*)p;               p = align_up(p + (size_t)NPART * 128 * BSTR * 4, 256);
  unsigned* xq = (unsigned*)p;       p = align_up(p + (size_t)N * IN, 256);          // fp8 x
  unsigned char* h1q = (unsigned char*)p;  p = align_up(p + (size_t)N * H, 256);     // fp8 h1
  unsigned short* B1 = (unsigned short*)p; p = align_up(p + (size_t)N * IN * 2, 256);
  unsigned short* B2 = (unsigned short*)p; p = align_up(p + (size_t)N * H * 2, 256);
  unsigned short* B3 = (unsigned short*)p; p = align_up(p + (size_t)N * H * 2, 256);
  unsigned short* Wt1a = (unsigned short*)p;  p = align_up(p + (size_t)H * IN * 2, 256);
  unsigned short* Wt1b = (unsigned short*)p;  p = align_up(p + (size_t)H * H * 2, 256);
  unsigned short* Wt2a = (unsigned short*)p;  p = align_up(p + (size_t)H * H * 2, 256);
  unsigned short* Wt2b = (unsigned short*)p;  p = align_up(p + (size_t)H * H * 2, 256);

  // 1: prep (edge binning via LDS sort + x->fp8 + weight transposes) — no memset needed
  prep_kernel<<<AB + XQ_BLOCKS + W1A_BLOCKS + 3 * WH_BLOCKS, 256, 0, stream>>>(
      srcp, dstp, pbuf, pcnt, x, xq, W1a, Wt1a, W1b, Wt1b, W2a, Wt2a, W2b, Wt2b);

  // 2: drain segments -> bucket CSR + deg
  csr_kernel<<<NPART, 256, 0, stream>>>(pbuf, pcnt, deg, csre);

  const int ggrid = (N + 127) / 128;   // 391

  // layer 1
  agg_pair_kernel<IN><<<N / 2, 64, 0, stream>>>((const unsigned char*)xq, deg, csre, eps1, B1);
  gemm_bf16_kernel<IN, true, false><<<ggrid, 256, 0, stream>>>(B1, Wt1a, b1a, B2, N);
  gemm_bf16_kernel<H, true, true><<<ggrid, 256, 0, stream>>>(B2, Wt1b, b1b, h1q, N);  // h1 -> fp8

  // layer 2
  agg_pair_kernel<H><<<N, 64, 0, stream>>>(h1q, deg, csre, eps2, B3);
  gemm_bf16_kernel<H, true, false><<<ggrid, 256, 0, stream>>>(B3, Wt2a, b2a, B2, N);
  gemm_bf16_kernel<H, false, false><<<ggrid, 256, 0, stream>>>(B2, Wt2b, b2b, B3, N); // B3 = h2

  // pool + classify
  pool_final_kernel<<<G, 128, 0, stream>>>(B3, batch, Wlin, blin, outp);
}